// Round 6
// baseline (70015.820 us; speedup 1.0000x reference)
//
#include <hip/hip_runtime.h>
#include <type_traits>

#define NWG   256
#define TPB_R 512     // persistent-register kernel: 8 waves, 2/SIMD, 256 VGPR
#define TPB_S 1024    // fallback streaming kernel
#define NSTEP 1000
#define NDATA 2048
#define WIDTH 4096

typedef __attribute__((ext_vector_type(4))) float f32x4;
typedef __attribute__((ext_vector_type(2))) float f32x2;
typedef __attribute__((ext_vector_type(2))) unsigned int u32x2;
typedef unsigned int uint;

#define SCHED_FENCE() __builtin_amdgcn_sched_barrier(0)

// ---------- scalar helpers ----------

__device__ __forceinline__ float sp_f(float v) {
  // jax.nn.softplus == max(v,0) + log1p(exp(-|v|))
  return fmaxf(v, 0.0f) + log1pf(expf(-fabsf(v)));
}

__device__ __forceinline__ float wred(float v) {
#pragma unroll
  for (int m = 32; m > 0; m >>= 1) v += __shfl_xor(v, m, 64);
  return v;
}

// ---------- waits / barriers (raw: compiler adds NO implicit drains) ----------

__device__ __forceinline__ void wait_vm0()   { asm volatile("s_waitcnt vmcnt(0)" ::: "memory"); SCHED_FENCE(); }
template<int N>
__device__ __forceinline__ void wait_vmN()   { asm volatile("s_waitcnt vmcnt(%0)" :: "n"(N) : "memory"); SCHED_FENCE(); }
__device__ __forceinline__ void wait_lgkm0() { asm volatile("s_waitcnt lgkmcnt(0)" ::: "memory"); SCHED_FENCE(); }
__device__ __forceinline__ void wgbar()      { __builtin_amdgcn_s_barrier(); SCHED_FENCE(); }

// ---------- L2-bypass (coherent) activation I/O ----------

__device__ __forceinline__ void st_sc_x1(float* p, float v) {
  asm volatile("global_store_dword %0, %1, off sc0 sc1" :: "v"(p), "v"(v) : "memory");
}
__device__ __forceinline__ void st_sc_x2(float* p, f32x2 v) {
  asm volatile("global_store_dwordx2 %0, %1, off sc0 sc1" :: "v"(p), "v"(v) : "memory");
}
__device__ __forceinline__ void ld_sc_x1_issue(const float* p, float& v) {
  asm volatile("global_load_dword %0, %1, off sc0 sc1" : "=v"(v) : "v"(p) : "memory");
}
__device__ __forceinline__ void ld_sc_x4_issue(const f32x4* p, f32x4& v) {
  asm volatile("global_load_dwordx4 %0, %1, off sc0 sc1" : "=v"(v) : "v"(p) : "memory");
}

// ---------- activation staging into LDS (bypass loads) ----------

__device__ __forceinline__ void stage4096_512(const float* src, float* xs, int tid) {
  f32x4 a, b;
  ld_sc_x4_issue((const f32x4*)src + tid, a);
  ld_sc_x4_issue((const f32x4*)src + tid + 512, b);
  wait_vm0();
  ((f32x4*)xs)[tid] = a;
  ((f32x4*)xs)[tid + 512] = b;
  wait_lgkm0();
  wgbar();
}
__device__ __forceinline__ void stage2048_512(const float* src, float* xs, int tid) {
  f32x4 a;
  ld_sc_x4_issue((const f32x4*)src + tid, a);
  wait_vm0();
  ((f32x4*)xs)[tid] = a;
  wait_lgkm0();
  wgbar();
}

// ---------- fence-free grid barrier (monotonic 2-level counter tree) ----------
// Caller guarantees every wave drained its activation store (vmcnt) first.

__device__ __forceinline__ void gbar(unsigned* gcnt, unsigned* root,
                                     unsigned b, int wg, int tid) {
  wgbar();
  if (tid == 0) {
    unsigned old = __hip_atomic_fetch_add(&gcnt[(wg >> 4) * 16], 1u,
                                          __ATOMIC_RELAXED, __HIP_MEMORY_SCOPE_AGENT);
    if ((old & 15u) == 15u)
      __hip_atomic_fetch_add(root, 1u, __ATOMIC_RELAXED, __HIP_MEMORY_SCOPE_AGENT);
    const unsigned target = 16u * (b + 1u);
    while (__hip_atomic_load(root, __ATOMIC_RELAXED, __HIP_MEMORY_SCOPE_AGENT) < target)
      __builtin_amdgcn_s_sleep(1);
  }
  wgbar();
}

// ---------- fp32 -> bf16 (RNE) weight conversion ----------

__device__ __forceinline__ uint bfr(float f) {
  uint u = __float_as_uint(f);
  return (u + 0x7fffu + ((u >> 16) & 1u)) >> 16;
}

__global__ void cvt_bf16(const float* __restrict__ in, uint* __restrict__ out, int n4) {
  int i = blockIdx.x * 256 + threadIdx.x;
  if (i >= n4) return;
  f32x4 v = ((const f32x4*)in)[i];
  u32x2 o;
  o.x = bfr(v.x) | (bfr(v.y) << 16);
  o.y = bfr(v.z) | (bfr(v.w) << 16);
  ((u32x2*)out)[i] = o;
}

// ---------- bf16-pair dot helpers (regs x LDS) ----------

template<int NI>
__device__ __forceinline__ void dot2(const u32x2* wa, const u32x2* wb,
                                     const float* xs, int lane,
                                     float& o0, float& o1) {
  const f32x4* x4 = (const f32x4*)xs;
  float s0 = 0.f, s1 = 0.f;
#pragma unroll
  for (int i = 0; i < NI; ++i) {
    f32x4 xv = x4[i * 64 + lane];
    uint a01 = wa[i].x, a23 = wa[i].y;
    uint b01 = wb[i].x, b23 = wb[i].y;
    s0 = fmaf(__uint_as_float(a01 << 16),         xv.x, s0);
    s0 = fmaf(__uint_as_float(a01 & 0xffff0000u), xv.y, s0);
    s0 = fmaf(__uint_as_float(a23 << 16),         xv.z, s0);
    s0 = fmaf(__uint_as_float(a23 & 0xffff0000u), xv.w, s0);
    s1 = fmaf(__uint_as_float(b01 << 16),         xv.x, s1);
    s1 = fmaf(__uint_as_float(b01 & 0xffff0000u), xv.y, s1);
    s1 = fmaf(__uint_as_float(b23 << 16),         xv.z, s1);
    s1 = fmaf(__uint_as_float(b23 & 0xffff0000u), xv.w, s1);
  }
  o0 = s0; o1 = s1;
}

template<int NI>
__device__ __forceinline__ float dot1(const u32x2* w, const float* xs, int lane) {
  const f32x4* x4 = (const f32x4*)xs;
  float s = 0.f;
#pragma unroll
  for (int i = 0; i < NI; ++i) {
    f32x4 xv = x4[i * 64 + lane];
    uint w01 = w[i].x, w23 = w[i].y;
    s = fmaf(__uint_as_float(w01 << 16),         xv.x, s);
    s = fmaf(__uint_as_float(w01 & 0xffff0000u), xv.y, s);
    s = fmaf(__uint_as_float(w23 << 16),         xv.z, s);
    s = fmaf(__uint_as_float(w23 & 0xffff0000u), xv.w, s);
  }
  return s;
}

// ======================================================================
// PERSISTENT-REGISTER kernel: entire bf16 weight set lives in VGPRs.
// Per CU (512 thr): 2 rows/wave of W0,W1,W2 + 1 row/wave of W3
//   = (2*8 + 2*16 + 2*16 + 16) u32x2 = 192 VGPR/thread of weights.
// Zero weight memory traffic inside the 1000-step loop.
// ======================================================================

__global__ void __launch_bounds__(TPB_R) ode_reg(
    const float* __restrict__ ts, const float* __restrict__ y0,
    const uint* __restrict__ W0b, const float* __restrict__ b0,
    const uint* __restrict__ W1b, const float* __restrict__ b1,
    const uint* __restrict__ W2b, const float* __restrict__ b2,
    const uint* __restrict__ W3b, const float* __restrict__ b3,
    float* __restrict__ out, float* hA, float* hB,
    unsigned* gcnt, unsigned* root)
{
  __shared__ float xs[WIDTH];
  const int wg = blockIdx.x, tid = threadIdx.x;
  const int wave = tid >> 6, lane = tid & 63;
  const float dt = ts[1] - ts[0];
  const int rw = wg * 16 + wave * 2;   // wide layers: 2 rows/wave
  const int rF = wg * 8 + wave;        // final layer: 1 row/wave

  // ---- prologue: load this thread's weight slices into registers ----
  u32x2 w0[2][8], w1[2][16], w2[2][16], wf[16];
  {
    const u32x2* p0 = (const u32x2*)W0b;
    const u32x2* p1 = (const u32x2*)W1b;
    const u32x2* p2 = (const u32x2*)W2b;
    const u32x2* p3 = (const u32x2*)W3b;
#pragma unroll
    for (int r = 0; r < 2; ++r) {
#pragma unroll
      for (int i = 0; i < 8; ++i)  w0[r][i] = p0[(size_t)(rw + r) * 512  + i * 64 + lane];
#pragma unroll
      for (int i = 0; i < 16; ++i) w1[r][i] = p1[(size_t)(rw + r) * 1024 + i * 64 + lane];
#pragma unroll
      for (int i = 0; i < 16; ++i) w2[r][i] = p2[(size_t)(rw + r) * 1024 + i * 64 + lane];
    }
#pragma unroll
    for (int i = 0; i < 16; ++i) wf[i] = p3[(size_t)rF * 1024 + i * 64 + lane];
  }
  const float bb0x = b0[rw], bb0y = b0[rw + 1];
  const float bb1x = b1[rw], bb1y = b1[rw + 1];
  const float bb2x = b2[rw], bb2y = b2[rw + 1];
  const float bf3  = b3[rF];

  unsigned b = 0;
  const float* yin = y0;
  for (int step = 0; step < NSTEP; ++step) {
    float a0, a1;
    // ---- L0: 2048 -> 4096, softplus ----
    stage2048_512(yin, xs, tid);
    dot2<8>(w0[0], w0[1], xs, lane, a0, a1);
    a0 = wred(a0); a1 = wred(a1);
    if (lane == 0) { f32x2 v; v.x = sp_f(a0 + bb0x); v.y = sp_f(a1 + bb0y); st_sc_x2(hA + rw, v); }
    wait_vm0();
    gbar(gcnt, root, b++, wg, tid);

    // ---- L1: 4096 -> 4096, softplus ----
    stage4096_512(hA, xs, tid);
    dot2<16>(w1[0], w1[1], xs, lane, a0, a1);
    a0 = wred(a0); a1 = wred(a1);
    if (lane == 0) { f32x2 v; v.x = sp_f(a0 + bb1x); v.y = sp_f(a1 + bb1y); st_sc_x2(hB + rw, v); }
    wait_vm0();
    gbar(gcnt, root, b++, wg, tid);

    // ---- L2: 4096 -> 4096, softplus ----
    stage4096_512(hB, xs, tid);
    dot2<16>(w2[0], w2[1], xs, lane, a0, a1);
    a0 = wred(a0); a1 = wred(a1);
    if (lane == 0) { f32x2 v; v.x = sp_f(a0 + bb2x); v.y = sp_f(a1 + bb2y); st_sc_x2(hA + rw, v); }
    wait_vm0();
    gbar(gcnt, root, b++, wg, tid);

    // ---- LF: 4096 -> 2048, y += dt*(W3 h + b3) ----
    stage4096_512(hA, xs, tid);
    float yo;
    ld_sc_x1_issue(yin + rF, yo);          // in flight during the dot
    float a = wred(dot1<16>(wf, xs, lane));
    wait_vm0();                            // yo ready
    float* yout = out + (size_t)step * NDATA;
    if (lane == 0) st_sc_x1(yout + rF, yo + dt * (a + bf3));
    wait_vm0();                            // drain y store before arrival
    gbar(gcnt, root, b++, wg, tid);
    yin = yout;                            // y state lives in d_out rows
  }
}

// ======================================================================
// FALLBACK (ws too small for bf16 buffers): round-5 fp32 streaming kernel.
// ======================================================================

__device__ __forceinline__ void issue_row_f32(const float* W, size_t elemidx, int lane, f32x4* wr, int ni) {
  const f32x4* p = (const f32x4*)(W + elemidx) + lane;
  for (int i = 0; i < ni; ++i)
    asm volatile("global_load_dwordx4 %0, %1, off" : "=v"(wr[i]) : "v"(p + i * 64) : "memory");
}

template<int NI>
__device__ __forceinline__ float dot_row_f32(const f32x4* wr, const float* xs, int xoff, int lane) {
  const f32x4* x4 = (const f32x4*)xs + xoff;
  float a = 0.f;
#pragma unroll
  for (int i = 0; i < NI; ++i) {
    f32x4 xv = x4[i * 64 + lane];
    a = fmaf(wr[i].x, xv.x, a); a = fmaf(wr[i].y, xv.y, a);
    a = fmaf(wr[i].z, xv.z, a); a = fmaf(wr[i].w, xv.w, a);
  }
  return a;
}

__device__ __forceinline__ void stage4096_1024(const float* src, float* xs, int tid) {
  f32x4 a;
  ld_sc_x4_issue((const f32x4*)src + tid, a);
  wait_vm0();
  ((f32x4*)xs)[tid] = a;
  wait_lgkm0();
  wgbar();
}
__device__ __forceinline__ void stage2048_1024(const float* src, float* xs, int tid) {
  f32x4 a;
  bool act = tid < 512;
  if (act) ld_sc_x4_issue((const f32x4*)src + tid, a);
  wait_vm0();
  if (act) ((f32x4*)xs)[tid] = a;
  wait_lgkm0();
  wgbar();
}

__global__ void __launch_bounds__(TPB_S, 1) ode_stream(
    const float* __restrict__ ts, const float* __restrict__ y0,
    const float* __restrict__ W0, const float* __restrict__ b0,
    const float* __restrict__ W1, const float* __restrict__ b1,
    const float* __restrict__ W2, const float* __restrict__ b2,
    const float* __restrict__ W3, const float* __restrict__ b3,
    float* __restrict__ out, float* hA, float* hB,
    unsigned* gcnt, unsigned* root)
{
  __shared__ float xs[WIDTH];
  __shared__ float ps[16];
  const int wg = blockIdx.x, tid = threadIdx.x;
  const int wave = tid >> 6, lane = tid & 63;
  const float dt = ts[1] - ts[0];
  const int rw = wg * 16 + wave;
  const int rF = wg * 8 + (wave >> 1);
  const int hf = wave & 1;

  f32x4 w0r[8], w1r[16], w2r[16], w3r[8];
  issue_row_f32(W0, (size_t)rw * NDATA, lane, w0r, 8);

  unsigned b = 0;
  const float* yin = y0;
  for (int step = 0; step < NSTEP; ++step) {
    stage2048_1024(yin, xs, tid);
    float a = wred(dot_row_f32<8>(w0r, xs, 0, lane));
    if (lane == 0) st_sc_x1(hA + rw, sp_f(a + b0[rw]));
    issue_row_f32(W1, (size_t)rw * WIDTH, lane, w1r, 16);
    wait_vmN<16>();
    gbar(gcnt, root, b++, wg, tid);

    stage4096_1024(hA, xs, tid);
    a = wred(dot_row_f32<16>(w1r, xs, 0, lane));
    if (lane == 0) st_sc_x1(hB + rw, sp_f(a + b1[rw]));
    issue_row_f32(W2, (size_t)rw * WIDTH, lane, w2r, 16);
    wait_vmN<16>();
    gbar(gcnt, root, b++, wg, tid);

    stage4096_1024(hB, xs, tid);
    a = wred(dot_row_f32<16>(w2r, xs, 0, lane));
    if (lane == 0) st_sc_x1(hA + rw, sp_f(a + b2[rw]));
    issue_row_f32(W3, (size_t)rF * WIDTH + (size_t)hf * 2048, lane, w3r, 8);
    wait_vmN<8>();
    gbar(gcnt, root, b++, wg, tid);

    stage4096_1024(hA, xs, tid);
    float yo;
    ld_sc_x1_issue(yin + rF, yo);
    a = wred(dot_row_f32<8>(w3r, xs, hf * 512, lane));
    if (lane == 0) ps[wave] = a;
    wait_lgkm0();
    wgbar();
    wait_vm0();
    float* yout = out + (size_t)step * NDATA;
    if (hf == 0 && lane == 0) {
      float tot = ps[wave] + ps[wave + 1];
      st_sc_x1(yout + rF, yo + dt * (tot + b3[rF]));
    }
    issue_row_f32(W0, (size_t)rw * NDATA, lane, w0r, 8);
    wait_vmN<8>();
    gbar(gcnt, root, b++, wg, tid);
    yin = yout;
  }
}

// ---------- launch ----------

#define WS_HA   0
#define WS_HB   16384
#define WS_CNT  32768
#define WS_WB   65536
static const size_t N_W0 = (size_t)WIDTH * NDATA;   // 8.39M
static const size_t N_W1 = (size_t)WIDTH * WIDTH;   // 16.78M
static const size_t N_W3 = (size_t)NDATA * WIDTH;   // 8.39M

extern "C" void kernel_launch(void* const* d_in, const int* in_sizes, int n_in,
                              void* d_out, int out_size, void* d_ws, size_t ws_size,
                              hipStream_t stream) {
  const float* ts = (const float*)d_in[0];
  const float* y0 = (const float*)d_in[1];
  const float* W0 = (const float*)d_in[2];
  const float* b0 = (const float*)d_in[3];
  const float* W1 = (const float*)d_in[4];
  const float* b1 = (const float*)d_in[5];
  const float* W2 = (const float*)d_in[6];
  const float* b2 = (const float*)d_in[7];
  const float* W3 = (const float*)d_in[8];
  const float* b3 = (const float*)d_in[9];
  float* out = (float*)d_out;

  char* ws = (char*)d_ws;
  float*    hA   = (float*)(ws + WS_HA);
  float*    hB   = (float*)(ws + WS_HB);
  unsigned* gcnt = (unsigned*)(ws + WS_CNT);
  unsigned* root = (unsigned*)(ws + WS_CNT + 1024);

  hipMemsetAsync(ws + WS_CNT, 0, 4096, stream);

  const size_t need = WS_WB + (N_W0 + 2 * N_W1 + N_W3) * 2;  // ~100.7 MB
  if (ws_size >= need) {
    uint* W0b = (uint*)(ws + WS_WB);
    uint* W1b = W0b + N_W0 / 2;
    uint* W2b = W1b + N_W1 / 2;
    uint* W3b = W2b + N_W1 / 2;
    hipLaunchKernelGGL(cvt_bf16, dim3((unsigned)(N_W0 / 4 / 256)), dim3(256), 0, stream, W0, W0b, (int)(N_W0 / 4));
    hipLaunchKernelGGL(cvt_bf16, dim3((unsigned)(N_W1 / 4 / 256)), dim3(256), 0, stream, W1, W1b, (int)(N_W1 / 4));
    hipLaunchKernelGGL(cvt_bf16, dim3((unsigned)(N_W1 / 4 / 256)), dim3(256), 0, stream, W2, W2b, (int)(N_W1 / 4));
    hipLaunchKernelGGL(cvt_bf16, dim3((unsigned)(N_W3 / 4 / 256)), dim3(256), 0, stream, W3, W3b, (int)(N_W3 / 4));
    hipLaunchKernelGGL(ode_reg, dim3(NWG), dim3(TPB_R), 0, stream,
                       ts, y0, W0b, b0, W1b, b1, W2b, b2, W3b, b3,
                       out, hA, hB, gcnt, root);
  } else {
    hipLaunchKernelGGL(ode_stream, dim3(NWG), dim3(TPB_S), 0, stream,
                       ts, y0, W0, b0, W1, b1, W2, b2, W3, b3,
                       out, hA, hB, gcnt, root);
  }
}

// Round 7
// 69869.440 us; speedup vs baseline: 1.0021x; 1.0021x over previous
//
#include <hip/hip_runtime.h>
#include <type_traits>

#define NWG   256
#define TPB_R 512     // persistent-register kernel: 8 waves, 2/SIMD, 256 VGPR cap
#define TPB_S 1024    // fallback streaming kernel
#define NSTEP 1000
#define NDATA 2048
#define WIDTH 4096

typedef __attribute__((ext_vector_type(4))) float f32x4;
typedef __attribute__((ext_vector_type(2))) float f32x2;
typedef __attribute__((ext_vector_type(2))) unsigned int u32x2;
typedef unsigned int uint;

#define SCHED_FENCE() __builtin_amdgcn_sched_barrier(0)

// ---------- scalar helpers ----------

__device__ __forceinline__ float sp_f(float v) {
  // jax.nn.softplus == max(v,0) + log1p(exp(-|v|))
  return fmaxf(v, 0.0f) + log1pf(expf(-fabsf(v)));
}

__device__ __forceinline__ float wred(float v) {
#pragma unroll
  for (int m = 32; m > 0; m >>= 1) v += __shfl_xor(v, m, 64);
  return v;
}

// ---------- waits / barriers (raw: compiler adds NO implicit drains) ----------

__device__ __forceinline__ void wait_vm0()   { asm volatile("s_waitcnt vmcnt(0)" ::: "memory"); SCHED_FENCE(); }
template<int N>
__device__ __forceinline__ void wait_vmN()   { asm volatile("s_waitcnt vmcnt(%0)" :: "n"(N) : "memory"); SCHED_FENCE(); }
__device__ __forceinline__ void wait_lgkm0() { asm volatile("s_waitcnt lgkmcnt(0)" ::: "memory"); SCHED_FENCE(); }
__device__ __forceinline__ void wgbar()      { __builtin_amdgcn_s_barrier(); SCHED_FENCE(); }

// ---------- L2-bypass (coherent) activation I/O ----------

__device__ __forceinline__ void st_sc_x1(float* p, float v) {
  asm volatile("global_store_dword %0, %1, off sc0 sc1" :: "v"(p), "v"(v) : "memory");
}
__device__ __forceinline__ void st_sc_x2(float* p, f32x2 v) {
  asm volatile("global_store_dwordx2 %0, %1, off sc0 sc1" :: "v"(p), "v"(v) : "memory");
}
__device__ __forceinline__ void ld_sc_x1_issue(const float* p, float& v) {
  asm volatile("global_load_dword %0, %1, off sc0 sc1" : "=v"(v) : "v"(p) : "memory");
}
__device__ __forceinline__ void ld_sc_x4_issue(const f32x4* p, f32x4& v) {
  asm volatile("global_load_dwordx4 %0, %1, off sc0 sc1" : "=v"(v) : "v"(p) : "memory");
}

// ---------- activation staging into LDS (bypass loads) ----------

__device__ __forceinline__ void stage4096_512(const float* src, float* xs, int tid) {
  f32x4 a, b;
  ld_sc_x4_issue((const f32x4*)src + tid, a);
  ld_sc_x4_issue((const f32x4*)src + tid + 512, b);
  wait_vm0();
  ((f32x4*)xs)[tid] = a;
  ((f32x4*)xs)[tid + 512] = b;
  wait_lgkm0();
  wgbar();
}
__device__ __forceinline__ void stage2048_512(const float* src, float* xs, int tid) {
  f32x4 a;
  ld_sc_x4_issue((const f32x4*)src + tid, a);
  wait_vm0();
  ((f32x4*)xs)[tid] = a;
  wait_lgkm0();
  wgbar();
}

// ---------- fence-free grid barrier (monotonic 2-level counter tree) ----------
// Caller guarantees every wave drained its activation store (vmcnt) first.

__device__ __forceinline__ void gbar(unsigned* gcnt, unsigned* root,
                                     unsigned b, int wg, int tid) {
  wgbar();
  if (tid == 0) {
    unsigned old = __hip_atomic_fetch_add(&gcnt[(wg >> 4) * 16], 1u,
                                          __ATOMIC_RELAXED, __HIP_MEMORY_SCOPE_AGENT);
    if ((old & 15u) == 15u)
      __hip_atomic_fetch_add(root, 1u, __ATOMIC_RELAXED, __HIP_MEMORY_SCOPE_AGENT);
    const unsigned target = 16u * (b + 1u);
    while (__hip_atomic_load(root, __ATOMIC_RELAXED, __HIP_MEMORY_SCOPE_AGENT) < target)
      __builtin_amdgcn_s_sleep(1);
  }
  wgbar();
}

// ---------- fp32 -> bf16 (RNE) weight conversion ----------

__device__ __forceinline__ uint bfr(float f) {
  uint u = __float_as_uint(f);
  return (u + 0x7fffu + ((u >> 16) & 1u)) >> 16;
}

__global__ void cvt_bf16(const float* __restrict__ in, uint* __restrict__ out, int n4) {
  int i = blockIdx.x * 256 + threadIdx.x;
  if (i >= n4) return;
  f32x4 v = ((const f32x4*)in)[i];
  u32x2 o;
  o.x = bfr(v.x) | (bfr(v.y) << 16);
  o.y = bfr(v.z) | (bfr(v.w) << 16);
  ((u32x2*)out)[i] = o;
}

// ---------- bf16-pair dot helpers (regs x LDS) ----------

template<int NI>
__device__ __forceinline__ void dot2(const u32x2* wa, const u32x2* wb,
                                     const float* xs, int lane,
                                     float& o0, float& o1) {
  const f32x4* x4 = (const f32x4*)xs;
  float s0 = 0.f, s1 = 0.f;
#pragma unroll
  for (int i = 0; i < NI; ++i) {
    f32x4 xv = x4[i * 64 + lane];
    uint a01 = wa[i].x, a23 = wa[i].y;
    uint b01 = wb[i].x, b23 = wb[i].y;
    s0 = fmaf(__uint_as_float(a01 << 16),         xv.x, s0);
    s0 = fmaf(__uint_as_float(a01 & 0xffff0000u), xv.y, s0);
    s0 = fmaf(__uint_as_float(a23 << 16),         xv.z, s0);
    s0 = fmaf(__uint_as_float(a23 & 0xffff0000u), xv.w, s0);
    s1 = fmaf(__uint_as_float(b01 << 16),         xv.x, s1);
    s1 = fmaf(__uint_as_float(b01 & 0xffff0000u), xv.y, s1);
    s1 = fmaf(__uint_as_float(b23 << 16),         xv.z, s1);
    s1 = fmaf(__uint_as_float(b23 & 0xffff0000u), xv.w, s1);
  }
  o0 = s0; o1 = s1;
}

template<int NI>
__device__ __forceinline__ float dot1(const u32x2* w, const float* xs, int lane) {
  const f32x4* x4 = (const f32x4*)xs;
  float s = 0.f;
#pragma unroll
  for (int i = 0; i < NI; ++i) {
    f32x4 xv = x4[i * 64 + lane];
    uint w01 = w[i].x, w23 = w[i].y;
    s = fmaf(__uint_as_float(w01 << 16),         xv.x, s);
    s = fmaf(__uint_as_float(w01 & 0xffff0000u), xv.y, s);
    s = fmaf(__uint_as_float(w23 << 16),         xv.z, s);
    s = fmaf(__uint_as_float(w23 & 0xffff0000u), xv.w, s);
  }
  return s;
}

// ======================================================================
// PERSISTENT-REGISTER kernel: entire bf16 weight set lives in VGPRs.
// Per CU (512 thr): 2 rows/wave of W0,W1,W2 + 1 row/wave of W3
//   = (2*8 + 2*16 + 2*16 + 16) u32x2 = 192 VGPR/thread of weights.
// __launch_bounds__(512, 2): 2 waves/EU -> 256-VGPR budget. Round 6's
// regression was the allocator capping at 128 VGPR and spilling all 192
// weight regs to scratch (FETCH_SIZE 50 GB = spill re-reads).
// ======================================================================

__global__ void __launch_bounds__(TPB_R, 2) ode_reg(
    const float* __restrict__ ts, const float* __restrict__ y0,
    const uint* __restrict__ W0b, const float* __restrict__ b0,
    const uint* __restrict__ W1b, const float* __restrict__ b1,
    const uint* __restrict__ W2b, const float* __restrict__ b2,
    const uint* __restrict__ W3b, const float* __restrict__ b3,
    float* __restrict__ out, float* hA, float* hB,
    unsigned* gcnt, unsigned* root)
{
  __shared__ float xs[WIDTH];
  const int wg = blockIdx.x, tid = threadIdx.x;
  const int wave = tid >> 6, lane = tid & 63;
  const float dt = ts[1] - ts[0];
  const int rw = wg * 16 + wave * 2;   // wide layers: 2 rows/wave
  const int rF = wg * 8 + wave;        // final layer: 1 row/wave

  // ---- prologue: load this thread's weight slices into registers ----
  u32x2 w0[2][8], w1[2][16], w2[2][16], wf[16];
  {
    const u32x2* p0 = (const u32x2*)W0b;
    const u32x2* p1 = (const u32x2*)W1b;
    const u32x2* p2 = (const u32x2*)W2b;
    const u32x2* p3 = (const u32x2*)W3b;
#pragma unroll
    for (int r = 0; r < 2; ++r) {
#pragma unroll
      for (int i = 0; i < 8; ++i)  w0[r][i] = p0[(size_t)(rw + r) * 512  + i * 64 + lane];
#pragma unroll
      for (int i = 0; i < 16; ++i) w1[r][i] = p1[(size_t)(rw + r) * 1024 + i * 64 + lane];
#pragma unroll
      for (int i = 0; i < 16; ++i) w2[r][i] = p2[(size_t)(rw + r) * 1024 + i * 64 + lane];
    }
#pragma unroll
    for (int i = 0; i < 16; ++i) wf[i] = p3[(size_t)rF * 1024 + i * 64 + lane];
  }
  const float bb0x = b0[rw], bb0y = b0[rw + 1];
  const float bb1x = b1[rw], bb1y = b1[rw + 1];
  const float bb2x = b2[rw], bb2y = b2[rw + 1];
  const float bf3  = b3[rF];

  unsigned b = 0;
  const float* yin = y0;
  for (int step = 0; step < NSTEP; ++step) {
    float a0, a1;
    // ---- L0: 2048 -> 4096, softplus ----
    stage2048_512(yin, xs, tid);
    dot2<8>(w0[0], w0[1], xs, lane, a0, a1);
    a0 = wred(a0); a1 = wred(a1);
    if (lane == 0) { f32x2 v; v.x = sp_f(a0 + bb0x); v.y = sp_f(a1 + bb0y); st_sc_x2(hA + rw, v); }
    wait_vm0();
    gbar(gcnt, root, b++, wg, tid);

    // ---- L1: 4096 -> 4096, softplus ----
    stage4096_512(hA, xs, tid);
    dot2<16>(w1[0], w1[1], xs, lane, a0, a1);
    a0 = wred(a0); a1 = wred(a1);
    if (lane == 0) { f32x2 v; v.x = sp_f(a0 + bb1x); v.y = sp_f(a1 + bb1y); st_sc_x2(hB + rw, v); }
    wait_vm0();
    gbar(gcnt, root, b++, wg, tid);

    // ---- L2: 4096 -> 4096, softplus ----
    stage4096_512(hB, xs, tid);
    dot2<16>(w2[0], w2[1], xs, lane, a0, a1);
    a0 = wred(a0); a1 = wred(a1);
    if (lane == 0) { f32x2 v; v.x = sp_f(a0 + bb2x); v.y = sp_f(a1 + bb2y); st_sc_x2(hA + rw, v); }
    wait_vm0();
    gbar(gcnt, root, b++, wg, tid);

    // ---- LF: 4096 -> 2048, y += dt*(W3 h + b3) ----
    stage4096_512(hA, xs, tid);
    float yo;
    ld_sc_x1_issue(yin + rF, yo);          // in flight during the dot
    float a = wred(dot1<16>(wf, xs, lane));
    wait_vm0();                            // yo ready
    float* yout = out + (size_t)step * NDATA;
    if (lane == 0) st_sc_x1(yout + rF, yo + dt * (a + bf3));
    wait_vm0();                            // drain y store before arrival
    gbar(gcnt, root, b++, wg, tid);
    yin = yout;                            // y state lives in d_out rows
  }
}

// ======================================================================
// FALLBACK (ws too small for bf16 buffers): round-5 fp32 streaming kernel.
// ======================================================================

__device__ __forceinline__ void issue_row_f32(const float* W, size_t elemidx, int lane, f32x4* wr, int ni) {
  const f32x4* p = (const f32x4*)(W + elemidx) + lane;
  for (int i = 0; i < ni; ++i)
    asm volatile("global_load_dwordx4 %0, %1, off" : "=v"(wr[i]) : "v"(p + i * 64) : "memory");
}

template<int NI>
__device__ __forceinline__ float dot_row_f32(const f32x4* wr, const float* xs, int xoff, int lane) {
  const f32x4* x4 = (const f32x4*)xs + xoff;
  float a = 0.f;
#pragma unroll
  for (int i = 0; i < NI; ++i) {
    f32x4 xv = x4[i * 64 + lane];
    a = fmaf(wr[i].x, xv.x, a); a = fmaf(wr[i].y, xv.y, a);
    a = fmaf(wr[i].z, xv.z, a); a = fmaf(wr[i].w, xv.w, a);
  }
  return a;
}

__device__ __forceinline__ void stage4096_1024(const float* src, float* xs, int tid) {
  f32x4 a;
  ld_sc_x4_issue((const f32x4*)src + tid, a);
  wait_vm0();
  ((f32x4*)xs)[tid] = a;
  wait_lgkm0();
  wgbar();
}
__device__ __forceinline__ void stage2048_1024(const float* src, float* xs, int tid) {
  f32x4 a;
  bool act = tid < 512;
  if (act) ld_sc_x4_issue((const f32x4*)src + tid, a);
  wait_vm0();
  if (act) ((f32x4*)xs)[tid] = a;
  wait_lgkm0();
  wgbar();
}

__global__ void __launch_bounds__(TPB_S, 1) ode_stream(
    const float* __restrict__ ts, const float* __restrict__ y0,
    const float* __restrict__ W0, const float* __restrict__ b0,
    const float* __restrict__ W1, const float* __restrict__ b1,
    const float* __restrict__ W2, const float* __restrict__ b2,
    const float* __restrict__ W3, const float* __restrict__ b3,
    float* __restrict__ out, float* hA, float* hB,
    unsigned* gcnt, unsigned* root)
{
  __shared__ float xs[WIDTH];
  __shared__ float ps[16];
  const int wg = blockIdx.x, tid = threadIdx.x;
  const int wave = tid >> 6, lane = tid & 63;
  const float dt = ts[1] - ts[0];
  const int rw = wg * 16 + wave;
  const int rF = wg * 8 + (wave >> 1);
  const int hf = wave & 1;

  f32x4 w0r[8], w1r[16], w2r[16], w3r[8];
  issue_row_f32(W0, (size_t)rw * NDATA, lane, w0r, 8);

  unsigned b = 0;
  const float* yin = y0;
  for (int step = 0; step < NSTEP; ++step) {
    stage2048_1024(yin, xs, tid);
    float a = wred(dot_row_f32<8>(w0r, xs, 0, lane));
    if (lane == 0) st_sc_x1(hA + rw, sp_f(a + b0[rw]));
    issue_row_f32(W1, (size_t)rw * WIDTH, lane, w1r, 16);
    wait_vmN<16>();
    gbar(gcnt, root, b++, wg, tid);

    stage4096_1024(hA, xs, tid);
    a = wred(dot_row_f32<16>(w1r, xs, 0, lane));
    if (lane == 0) st_sc_x1(hB + rw, sp_f(a + b1[rw]));
    issue_row_f32(W2, (size_t)rw * WIDTH, lane, w2r, 16);
    wait_vmN<16>();
    gbar(gcnt, root, b++, wg, tid);

    stage4096_1024(hB, xs, tid);
    a = wred(dot_row_f32<16>(w2r, xs, 0, lane));
    if (lane == 0) st_sc_x1(hA + rw, sp_f(a + b2[rw]));
    issue_row_f32(W3, (size_t)rF * WIDTH + (size_t)hf * 2048, lane, w3r, 8);
    wait_vmN<8>();
    gbar(gcnt, root, b++, wg, tid);

    stage4096_1024(hA, xs, tid);
    float yo;
    ld_sc_x1_issue(yin + rF, yo);
    a = wred(dot_row_f32<8>(w3r, xs, hf * 512, lane));
    if (lane == 0) ps[wave] = a;
    wait_lgkm0();
    wgbar();
    wait_vm0();
    float* yout = out + (size_t)step * NDATA;
    if (hf == 0 && lane == 0) {
      float tot = ps[wave] + ps[wave + 1];
      st_sc_x1(yout + rF, yo + dt * (tot + b3[rF]));
    }
    issue_row_f32(W0, (size_t)rw * NDATA, lane, w0r, 8);
    wait_vmN<8>();
    gbar(gcnt, root, b++, wg, tid);
    yin = yout;
  }
}

// ---------- launch ----------

#define WS_HA   0
#define WS_HB   16384
#define WS_CNT  32768
#define WS_WB   65536
static const size_t N_W0 = (size_t)WIDTH * NDATA;   // 8.39M
static const size_t N_W1 = (size_t)WIDTH * WIDTH;   // 16.78M
static const size_t N_W3 = (size_t)NDATA * WIDTH;   // 8.39M

extern "C" void kernel_launch(void* const* d_in, const int* in_sizes, int n_in,
                              void* d_out, int out_size, void* d_ws, size_t ws_size,
                              hipStream_t stream) {
  const float* ts = (const float*)d_in[0];
  const float* y0 = (const float*)d_in[1];
  const float* W0 = (const float*)d_in[2];
  const float* b0 = (const float*)d_in[3];
  const float* W1 = (const float*)d_in[4];
  const float* b1 = (const float*)d_in[5];
  const float* W2 = (const float*)d_in[6];
  const float* b2 = (const float*)d_in[7];
  const float* W3 = (const float*)d_in[8];
  const float* b3 = (const float*)d_in[9];
  float* out = (float*)d_out;

  char* ws = (char*)d_ws;
  float*    hA   = (float*)(ws + WS_HA);
  float*    hB   = (float*)(ws + WS_HB);
  unsigned* gcnt = (unsigned*)(ws + WS_CNT);
  unsigned* root = (unsigned*)(ws + WS_CNT + 1024);

  hipMemsetAsync(ws + WS_CNT, 0, 4096, stream);

  const size_t need = WS_WB + (N_W0 + 2 * N_W1 + N_W3) * 2;  // ~100.7 MB
  if (ws_size >= need) {
    uint* W0b = (uint*)(ws + WS_WB);
    uint* W1b = W0b + N_W0 / 2;
    uint* W2b = W1b + N_W1 / 2;
    uint* W3b = W2b + N_W1 / 2;
    hipLaunchKernelGGL(cvt_bf16, dim3((unsigned)(N_W0 / 4 / 256)), dim3(256), 0, stream, W0, W0b, (int)(N_W0 / 4));
    hipLaunchKernelGGL(cvt_bf16, dim3((unsigned)(N_W1 / 4 / 256)), dim3(256), 0, stream, W1, W1b, (int)(N_W1 / 4));
    hipLaunchKernelGGL(cvt_bf16, dim3((unsigned)(N_W1 / 4 / 256)), dim3(256), 0, stream, W2, W2b, (int)(N_W1 / 4));
    hipLaunchKernelGGL(cvt_bf16, dim3((unsigned)(N_W3 / 4 / 256)), dim3(256), 0, stream, W3, W3b, (int)(N_W3 / 4));
    hipLaunchKernelGGL(ode_reg, dim3(NWG), dim3(TPB_R), 0, stream,
                       ts, y0, W0b, b0, W1b, b1, W2b, b2, W3b, b3,
                       out, hA, hB, gcnt, root);
  } else {
    hipLaunchKernelGGL(ode_stream, dim3(NWG), dim3(TPB_S), 0, stream,
                       ts, y0, W0, b0, W1, b1, W2, b2, W3, b3,
                       out, hA, hB, gcnt, root);
  }
}